// Round 1
// baseline (205.147 us; speedup 1.0000x reference)
//
#include <hip/hip_runtime.h>

// LearnedClassVectors: bucketize fp32 volume into 10 HU bins, gather (10,12)
// embedding, re-tile into 4x4x4 patches -> out (B=2, 768, 32, 32, 32) fp32.
//
// Block = one (b, gd, gh) tile: stages 4x4x128 slab of bins (packed bytes) +
// the 120-float table in LDS, then streams 768*32 floats out as float4 with
// gw as the contiguous axis (full 128B cache-line writes).

#define NBLOCKS 2048
#define NTHREADS 256

__global__ __launch_bounds__(NTHREADS) void lcv_kernel(
    const float* __restrict__ x,
    const float* __restrict__ vectors,
    float* __restrict__ out)
{
    // bins: 16 (pd,ph) rows x 4 pw x 32 gw bytes = 2048 B, viewed as dwords so a
    // single ds_read_b32 yields 4 gw-consecutive bins. Layout: [pd][ph][pw][gw].
    __shared__ unsigned int s_bins[512];
    __shared__ float s_vec[120];

    const int tid = threadIdx.x;
    const int bid = blockIdx.x;
    const int b   = bid >> 10;        // 2
    const int gd  = (bid >> 5) & 31;  // 32
    const int gh  = bid & 31;         // 32

    if (tid < 120) s_vec[tid] = vectors[tid];

    // ---- Stage 1: load x slab (d in gd*4..+4, h in gh*4..+4, all w) -> bins ----
    const float4* x4 = (const float4*)(x + ((size_t)b << 21)); // b * 128^3
    unsigned char* s_b8 = (unsigned char*)s_bins;
    #pragma unroll
    for (int j = tid; j < 512; j += NTHREADS) {
        const int ddhh = j >> 5;   // 0..15  (dd*4 + hh)
        const int w4   = j & 31;   // gw index (float4 along w)
        const int dd = ddhh >> 2, hh = ddhh & 3;
        const int d = (gd << 2) + dd, h = (gh << 2) + hh;
        const float4 xv = x4[(((d << 7) + h) << 5) + w4];
        const float vals[4] = {xv.x, xv.y, xv.z, xv.w};
        #pragma unroll
        for (int pw = 0; pw < 4; ++pw) {
            const float xx = vals[pw];
            // searchsorted(side='right') == count(edges <= x)
            int bin = (xx >= -1000.f) + (xx >= -75.f) + (xx >= 0.f)
                    + (xx >= 15.f)   + (xx >= 25.f)  + (xx >= 40.f)
                    + (xx >= 50.f)   + (xx >= 200.f) + (xx >= 1000.f);
            // byte addr = ((ddhh*4 + pw) * 32) + gw   -> row == p for consumer
            s_b8[((ddhh << 2) + pw) * 32 + w4] = (unsigned char)bin;
        }
    }
    __syncthreads();

    // ---- Stage 2: stream output. o = ((pd*4+ph)*4+pw)*12 + v, p = o/12 ----
    const int gw4   = tid & 7;   // float4 index along gw
    const int obase = tid >> 3;  // 0..31
    // out flat base (floats): b*768*32768 + gd*1024 + gh*32  (16B-aligned)
    float4* out4 = (float4*)(out + (size_t)b * (768u * 32768u)
                                  + (gd << 10) + (gh << 5));
    #pragma unroll 4
    for (int iter = 0; iter < 24; ++iter) {
        const int o = (iter << 5) + obase;
        const int p = o / 12;          // magic-mul
        const int v = o - p * 12;
        const unsigned bins = s_bins[(p << 3) + gw4]; // 4 packed bins
        float4 r;
        r.x = s_vec[(bins & 0xffu) * 12u + v];
        r.y = s_vec[((bins >> 8) & 0xffu) * 12u + v];
        r.z = s_vec[((bins >> 16) & 0xffu) * 12u + v];
        r.w = s_vec[(bins >> 24) * 12u + v];
        out4[o * 8192 + gw4] = r;      // contiguous 128B per 8 lanes
    }
}

extern "C" void kernel_launch(void* const* d_in, const int* in_sizes, int n_in,
                              void* d_out, int out_size, void* d_ws, size_t ws_size,
                              hipStream_t stream) {
    const float* x       = (const float*)d_in[0];
    const float* vectors = (const float*)d_in[1];
    float* out           = (float*)d_out;
    lcv_kernel<<<NBLOCKS, NTHREADS, 0, stream>>>(x, vectors, out);
}